// Round 1
// baseline (803.611 us; speedup 1.0000x reference)
//
#include <hip/hip_runtime.h>

#define TT 512
#define HIDD 2048
#define NH 16
#define NKV 8
#define DD 128
#define INTR 6144
#define SEQ 4096
#define SCALE 0.08838834764831845f

typedef __attribute__((ext_vector_type(8))) short short8;
typedef __attribute__((ext_vector_type(4))) float floatx4;

static __device__ __forceinline__ unsigned short f2b(float f) {
  unsigned int u = __float_as_uint(f);
  u += 0x7fffu + ((u >> 16) & 1u);
  return (unsigned short)(u >> 16);
}

// ---------------- GEMM core: C(128x128) += A(128xK) * B(128xK)^T ----------------
// LDS rows padded to 40 bf16 (80B = 5*16B, keeps 16B alignment, 2-way bank alias = free)

static __device__ __forceinline__ void stage_f32(const float* __restrict__ src, int ld, int k0,
                                                 unsigned short* dst, int tid) {
  const int r0 = tid >> 3;
  const int c4 = (tid & 7) << 2;
#pragma unroll
  for (int i = 0; i < 4; ++i) {
    const int row = r0 + (i << 5);
    const float4 v = *reinterpret_cast<const float4*>(src + (size_t)row * ld + k0 + c4);
    ushort4 h;
    h.x = f2b(v.x); h.y = f2b(v.y); h.z = f2b(v.z); h.w = f2b(v.w);
    *reinterpret_cast<ushort4*>(dst + row * 40 + c4) = h;
  }
}

static __device__ __forceinline__ void stage_b16(const unsigned short* __restrict__ src, int ld, int k0,
                                                 unsigned short* dst, int tid) {
  const int r0 = tid >> 2;
  const int c8 = (tid & 3) << 3;
#pragma unroll
  for (int i = 0; i < 2; ++i) {
    const int row = r0 + (i << 6);
    short8 v = *reinterpret_cast<const short8*>(src + (size_t)row * ld + k0 + c8);
    *reinterpret_cast<short8*>(dst + row * 40 + c8) = v;
  }
}

template <bool A16, bool B16>
static __device__ __forceinline__ void gemm_core(const void* __restrict__ A, int lda,
                                                 const void* __restrict__ B, int ldb, int K,
                                                 floatx4 acc[4][4],
                                                 unsigned short* As, unsigned short* Bs) {
  const int tid = threadIdx.x;
  const int lane = tid & 63;
  const int wave = tid >> 6;
  const int wr = (wave >> 1) << 6;
  const int wc = (wave & 1) << 6;
  const int lrow = lane & 15;
  const int koff = (lane >> 4) << 3;
  for (int k0 = 0; k0 < K; k0 += 32) {
    if (A16) stage_b16((const unsigned short*)A, lda, k0, As, tid);
    else     stage_f32((const float*)A, lda, k0, As, tid);
    if (B16) stage_b16((const unsigned short*)B, ldb, k0, Bs, tid);
    else     stage_f32((const float*)B, ldb, k0, Bs, tid);
    __syncthreads();
    short8 af[4], bfr[4];
#pragma unroll
    for (int mi = 0; mi < 4; ++mi)
      af[mi] = *reinterpret_cast<const short8*>(As + (wr + mi * 16 + lrow) * 40 + koff);
#pragma unroll
    for (int ni = 0; ni < 4; ++ni)
      bfr[ni] = *reinterpret_cast<const short8*>(Bs + (wc + ni * 16 + lrow) * 40 + koff);
#pragma unroll
    for (int mi = 0; mi < 4; ++mi)
#pragma unroll
      for (int ni = 0; ni < 4; ++ni)
        acc[mi][ni] = __builtin_amdgcn_mfma_f32_16x16x32_bf16(af[mi], bfr[ni], acc[mi][ni], 0, 0, 0);
    __syncthreads();
  }
}

#define EPI_VARS \
  const int lane = threadIdx.x & 63; \
  const int wave = threadIdx.x >> 6; \
  const int wr = (wave >> 1) << 6;   \
  const int wc = (wave & 1) << 6;    \
  const int lrow = lane & 15;        \
  const int quad = lane >> 4;

#define ZERO_ACC \
  floatx4 acc[4][4]; \
  _Pragma("unroll") for (int mi = 0; mi < 4; ++mi) \
  _Pragma("unroll") for (int ni = 0; ni < 4; ++ni) { floatx4 z = {0.f,0.f,0.f,0.f}; acc[mi][ni] = z; }

// XCD swizzle decode: all 4 m-tiles of an n-tile land on the same XCD (bid%8 const)
#define SWZ_DECODE \
  const int bid = blockIdx.x; \
  const int mt = (bid >> 3) & 3; \
  const int nt = (((bid >> 3) >> 2) << 3) + (bid & 7); \
  const int m0 = mt << 7, n0 = nt << 7;

// ---------------- kernels ----------------

__global__ __launch_bounds__(256) void k_rms1(const float* __restrict__ conv,
                                              const float* __restrict__ w,
                                              float* __restrict__ xb, float* __restrict__ h1) {
  const int t = blockIdx.x;
  const int tid = threadIdx.x;
  float v[8];
  float ss = 0.f;
#pragma unroll
  for (int i = 0; i < 8; ++i) {
    const int c = tid + (i << 8);
    v[i] = conv[(size_t)c * TT + t];
    ss += v[i] * v[i];
  }
  __shared__ float red[4];
  const int lane = tid & 63, wid = tid >> 6;
#pragma unroll
  for (int o = 32; o; o >>= 1) ss += __shfl_xor(ss, o);
  if (!lane) red[wid] = ss;
  __syncthreads();
  const float tot = red[0] + red[1] + red[2] + red[3];
  const float r = rsqrtf(tot * (1.0f / HIDD) + 1e-6f);
#pragma unroll
  for (int i = 0; i < 8; ++i) {
    const int c = tid + (i << 8);
    xb[(size_t)t * HIDD + c] = v[i];
    h1[(size_t)t * HIDD + c] = v[i] * r * w[c];
  }
}

__global__ __launch_bounds__(256) void k_rms2(const float* __restrict__ hid,
                                              const float* __restrict__ w,
                                              float* __restrict__ h2) {
  const int t = blockIdx.x;
  const int tid = threadIdx.x;
  float v[8];
  float ss = 0.f;
#pragma unroll
  for (int i = 0; i < 8; ++i) {
    const int c = tid + (i << 8);
    v[i] = hid[(size_t)t * HIDD + c];
    ss += v[i] * v[i];
  }
  __shared__ float red[4];
  const int lane = tid & 63, wid = tid >> 6;
#pragma unroll
  for (int o = 32; o; o >>= 1) ss += __shfl_xor(ss, o);
  if (!lane) red[wid] = ss;
  __syncthreads();
  const float tot = red[0] + red[1] + red[2] + red[3];
  const float r = rsqrtf(tot * (1.0f / HIDD) + 1e-6f);
#pragma unroll
  for (int i = 0; i < 8; ++i) {
    const int c = tid + (i << 8);
    h2[(size_t)t * HIDD + c] = v[i] * r * w[c];
  }
}

__global__ __launch_bounds__(256) void k_gemm_qkv(const float* __restrict__ h1,
                                                  const float* __restrict__ wq,
                                                  const float* __restrict__ wk,
                                                  const float* __restrict__ wv,
                                                  float* __restrict__ qkv) {
  __shared__ unsigned short As[128 * 40], Bs[128 * 40];
  SWZ_DECODE
  const float* Bp;
  if (n0 < 2048)      Bp = wq + (size_t)n0 * HIDD;
  else if (n0 < 3072) Bp = wk + (size_t)(n0 - 2048) * HIDD;
  else                Bp = wv + (size_t)(n0 - 3072) * HIDD;
  ZERO_ACC
  gemm_core<false, false>(h1 + (size_t)m0 * HIDD, HIDD, Bp, HIDD, HIDD, acc, As, Bs);
  EPI_VARS
#pragma unroll
  for (int mi = 0; mi < 4; ++mi)
#pragma unroll
    for (int ni = 0; ni < 4; ++ni)
#pragma unroll
      for (int rr = 0; rr < 4; ++rr) {
        const int row = m0 + wr + mi * 16 + quad * 4 + rr;
        const int col = n0 + wc + ni * 16 + lrow;
        qkv[(size_t)row * 4096 + col] = acc[mi][ni][rr];
      }
}

__global__ __launch_bounds__(128) void k_rope(const float* __restrict__ qkv,
                                              const float* __restrict__ cosb,
                                              const float* __restrict__ sinb,
                                              const float* __restrict__ qnw,
                                              const float* __restrict__ knw,
                                              unsigned short* __restrict__ qb,
                                              unsigned short* __restrict__ kb,
                                              unsigned short* __restrict__ vtb,
                                              float* __restrict__ kout,
                                              float* __restrict__ vout) {
  const int u = blockIdx.x;  // 0..15 q-heads, 16..23 k-heads, 24..31 v-heads
  const int t = blockIdx.y;
  const int d = threadIdx.x;
  __shared__ float red[2];
  __shared__ float sh[DD];
  float val;
  if (u < NH)            val = qkv[(size_t)t * 4096 + u * DD + d];
  else if (u < NH + NKV) val = qkv[(size_t)t * 4096 + 2048 + (u - NH) * DD + d];
  else                   val = qkv[(size_t)t * 4096 + 3072 + (u - NH - NKV) * DD + d];
  if (u < NH + NKV) {
    float ss = val * val;
    const int lane = d & 63, wid = d >> 6;
#pragma unroll
    for (int o = 32; o; o >>= 1) ss += __shfl_xor(ss, o);
    if (!lane) red[wid] = ss;
    __syncthreads();
    const float r = rsqrtf((red[0] + red[1]) * (1.0f / DD) + 1e-6f);
    const float w = (u < NH) ? qnw[d] : knw[d];
    const float nv = val * r * w;
    sh[d] = nv;
    __syncthreads();
    const float partner = sh[d ^ 64];
    const float rh = (d < 64) ? -partner : partner;
    const float o = nv * cosb[(size_t)t * DD + d] + rh * sinb[(size_t)t * DD + d];
    if (u < NH) {
      qb[(size_t)u * TT * DD + (size_t)t * DD + d] = f2b(o);
    } else {
      const int kh = u - NH;
      kout[(size_t)kh * SEQ * DD + (size_t)t * DD + d] = o;
      kb[(size_t)kh * TT * DD + (size_t)t * DD + d] = f2b(o);
    }
  } else {
    const int vh = u - NH - NKV;
    vout[(size_t)vh * SEQ * DD + (size_t)t * DD + d] = val;
    vtb[(size_t)vh * DD * TT + (size_t)d * TT + t] = f2b(val);
  }
}

__global__ __launch_bounds__(256) void k_tail(const float* __restrict__ kc,
                                              const float* __restrict__ vc,
                                              float* __restrict__ ko,
                                              float* __restrict__ vo) {
  const int i = blockIdx.x * 256 + threadIdx.x;  // float4 index, total NKV*SEQ*DD/4
  const int e = i << 2;
  const int s = (e >> 7) & (SEQ - 1);
  if (s >= TT) {
    reinterpret_cast<float4*>(ko)[i] = reinterpret_cast<const float4*>(kc)[i];
    reinterpret_cast<float4*>(vo)[i] = reinterpret_cast<const float4*>(vc)[i];
  }
}

__global__ __launch_bounds__(256) void k_scores(const unsigned short* __restrict__ qb,
                                                const unsigned short* __restrict__ kb,
                                                float* __restrict__ sc) {
  __shared__ unsigned short As[128 * 40], Bs[128 * 40];
  const int m0 = blockIdx.x << 7, n0 = blockIdx.y << 7, h = blockIdx.z;
  ZERO_ACC
  gemm_core<true, true>(qb + (size_t)h * TT * DD + (size_t)m0 * DD, DD,
                        kb + (size_t)(h >> 1) * TT * DD + (size_t)n0 * DD, DD, DD, acc, As, Bs);
  EPI_VARS
  float* out = sc + (size_t)h * TT * TT;
#pragma unroll
  for (int mi = 0; mi < 4; ++mi)
#pragma unroll
    for (int ni = 0; ni < 4; ++ni)
#pragma unroll
      for (int rr = 0; rr < 4; ++rr) {
        const int t = m0 + wr + mi * 16 + quad * 4 + rr;
        const int s = n0 + wc + ni * 16 + lrow;
        float v = acc[mi][ni][rr] * SCALE;
        if (s > t) v += -10000.0f;
        out[(size_t)t * TT + s] = v;
      }
}

__global__ __launch_bounds__(256) void k_softmax(const float* __restrict__ sc,
                                                 unsigned short* __restrict__ Pb) {
  const int h = blockIdx.x >> 9, t = blockIdx.x & 511;
  const int tid = threadIdx.x;
  const float* row = sc + ((size_t)h * TT + t) * TT;
  float v0 = row[tid], v1 = row[tid + 256];
  __shared__ float red[4];
  const int lane = tid & 63, wid = tid >> 6;
  float m = fmaxf(v0, v1);
#pragma unroll
  for (int o = 32; o; o >>= 1) m = fmaxf(m, __shfl_xor(m, o));
  if (!lane) red[wid] = m;
  __syncthreads();
  m = fmaxf(fmaxf(red[0], red[1]), fmaxf(red[2], red[3]));
  const float e0 = __expf(v0 - m), e1 = __expf(v1 - m);
  float s = e0 + e1;
  __syncthreads();
#pragma unroll
  for (int o = 32; o; o >>= 1) s += __shfl_xor(s, o);
  if (!lane) red[wid] = s;
  __syncthreads();
  const float inv = 1.0f / (red[0] + red[1] + red[2] + red[3]);
  unsigned short* orow = Pb + ((size_t)h * TT + t) * TT;
  orow[tid] = f2b(e0 * inv);
  orow[tid + 256] = f2b(e1 * inv);
}

__global__ __launch_bounds__(256) void k_pv(const unsigned short* __restrict__ Pb,
                                            const unsigned short* __restrict__ vtb,
                                            float* __restrict__ o_in) {
  __shared__ unsigned short As[128 * 40], Bs[128 * 40];
  const int m0 = blockIdx.x << 7, h = blockIdx.z;
  ZERO_ACC
  gemm_core<true, true>(Pb + (size_t)h * TT * TT + (size_t)m0 * TT, TT,
                        vtb + (size_t)(h >> 1) * DD * TT, TT, TT, acc, As, Bs);
  EPI_VARS
#pragma unroll
  for (int mi = 0; mi < 4; ++mi)
#pragma unroll
    for (int ni = 0; ni < 4; ++ni)
#pragma unroll
      for (int rr = 0; rr < 4; ++rr) {
        const int row = m0 + wr + mi * 16 + quad * 4 + rr;
        const int col = wc + ni * 16 + lrow;
        o_in[(size_t)row * HIDD + h * DD + col] = acc[mi][ni][rr];
      }
}

__global__ __launch_bounds__(256) void k_gemm_o(const float* __restrict__ o_in,
                                                const float* __restrict__ wo,
                                                const float* __restrict__ xb,
                                                float* __restrict__ hidden) {
  __shared__ unsigned short As[128 * 40], Bs[128 * 40];
  SWZ_DECODE
  ZERO_ACC
  gemm_core<false, false>(o_in + (size_t)m0 * HIDD, HIDD, wo + (size_t)n0 * HIDD, HIDD, HIDD, acc, As, Bs);
  EPI_VARS
#pragma unroll
  for (int mi = 0; mi < 4; ++mi)
#pragma unroll
    for (int ni = 0; ni < 4; ++ni)
#pragma unroll
      for (int rr = 0; rr < 4; ++rr) {
        const int row = m0 + wr + mi * 16 + quad * 4 + rr;
        const int col = n0 + wc + ni * 16 + lrow;
        const size_t idx = (size_t)row * HIDD + col;
        hidden[idx] = xb[idx] + acc[mi][ni][rr];
      }
}

__global__ __launch_bounds__(256) void k_gemm_gu(const float* __restrict__ h2,
                                                 const float* __restrict__ wgu,
                                                 float* __restrict__ gu) {
  __shared__ unsigned short As[128 * 40], Bs[128 * 40];
  SWZ_DECODE
  ZERO_ACC
  gemm_core<false, false>(h2 + (size_t)m0 * HIDD, HIDD, wgu + (size_t)n0 * HIDD, HIDD, HIDD, acc, As, Bs);
  EPI_VARS
#pragma unroll
  for (int mi = 0; mi < 4; ++mi)
#pragma unroll
    for (int ni = 0; ni < 4; ++ni)
#pragma unroll
      for (int rr = 0; rr < 4; ++rr) {
        const int row = m0 + wr + mi * 16 + quad * 4 + rr;
        const int col = n0 + wc + ni * 16 + lrow;
        gu[(size_t)row * (2 * INTR) + col] = acc[mi][ni][rr];
      }
}

__global__ __launch_bounds__(256) void k_silu(const float* __restrict__ gu,
                                              float* __restrict__ act) {
  const int j = blockIdx.x * 256 + threadIdx.x;  // 0..6143
  const int t = blockIdx.y;
  const float g = gu[(size_t)t * (2 * INTR) + j];
  const float u = gu[(size_t)t * (2 * INTR) + INTR + j];
  act[(size_t)t * INTR + j] = g / (1.f + __expf(-g)) * u;
}

__global__ __launch_bounds__(256) void k_gemm_down(const float* __restrict__ act,
                                                   const float* __restrict__ wdn,
                                                   const float* __restrict__ hidden,
                                                   float* __restrict__ out0) {
  __shared__ unsigned short As[128 * 40], Bs[128 * 40];
  SWZ_DECODE
  ZERO_ACC
  gemm_core<false, false>(act + (size_t)m0 * INTR, INTR, wdn + (size_t)n0 * INTR, INTR, INTR, acc, As, Bs);
  EPI_VARS
#pragma unroll
  for (int mi = 0; mi < 4; ++mi)
#pragma unroll
    for (int ni = 0; ni < 4; ++ni) {
      const int row0 = m0 + wr + mi * 16 + quad * 4;
      const int c = n0 + wc + ni * 16 + lrow;
      float4 o;
      o.x = hidden[(size_t)(row0 + 0) * HIDD + c] + acc[mi][ni][0];
      o.y = hidden[(size_t)(row0 + 1) * HIDD + c] + acc[mi][ni][1];
      o.z = hidden[(size_t)(row0 + 2) * HIDD + c] + acc[mi][ni][2];
      o.w = hidden[(size_t)(row0 + 3) * HIDD + c] + acc[mi][ni][3];
      *reinterpret_cast<float4*>(out0 + (size_t)c * TT + row0) = o;  // transposed store
    }
}

extern "C" void kernel_launch(void* const* d_in, const int* in_sizes, int n_in,
                              void* d_out, int out_size, void* d_ws, size_t ws_size,
                              hipStream_t stream) {
  const float* conv   = (const float*)d_in[0];
  const float* cosb   = (const float*)d_in[1];
  const float* sinb   = (const float*)d_in[2];
  const float* kcache = (const float*)d_in[5];
  const float* vcache = (const float*)d_in[6];
  const float* wq  = (const float*)d_in[7];
  const float* wk  = (const float*)d_in[8];
  const float* wv  = (const float*)d_in[9];
  const float* wo  = (const float*)d_in[10];
  const float* ln1 = (const float*)d_in[11];
  const float* ln2 = (const float*)d_in[12];
  const float* qnw = (const float*)d_in[13];
  const float* knw = (const float*)d_in[14];
  const float* wgu = (const float*)d_in[15];
  const float* wdn = (const float*)d_in[16];

  float* ws = (float*)d_ws;
  // workspace layout (floats), with lifetime-based aliasing; total 17,825,792 f = 68 MB
  float* xb     = ws + 0;                               // 1,048,576   x (t,c)
  float* h1     = ws + 1048576;                         // 1,048,576   h1; later o_in
  float* o_in   = h1;
  float* qkv    = ws + 2097152;                         // 2,097,152   qkv; later h2
  float* h2     = qkv;
  float* hidden = ws + 4194304;                         // 1,048,576
  unsigned short* qb  = (unsigned short*)(ws + 5242880);  // 16*512*128 bf16
  unsigned short* kb  = qb + 1048576;                     // 8*512*128 bf16
  unsigned short* vtb = kb + 524288;                      // 8*128*512 bf16 (transposed)
  float* sc  = ws + 6291456;                            // 4,194,304 scores; later gu (6,291,456)
  float* gu  = sc;
  unsigned short* Pb = (unsigned short*)(ws + 12582912);  // 16*512*512 bf16
  float* act = ws + 14680064;                           // 3,145,728

  float* out0 = (float*)d_out;          // (HID, T) transposed hidden_out
  float* kout = out0 + 1048576;         // (NKV, SEQ, D)
  float* vout = kout + 4194304;         // (NKV, SEQ, D)

  k_rms1<<<TT, 256, 0, stream>>>(conv, ln1, xb, h1);
  k_gemm_qkv<<<128, 256, 0, stream>>>(h1, wq, wk, wv, qkv);
  k_rope<<<dim3(NH + 2 * NKV, TT), 128, 0, stream>>>(qkv, cosb, sinb, qnw, knw, qb, kb, vtb, kout, vout);
  k_tail<<<4096, 256, 0, stream>>>(kcache, vcache, kout, vout);
  k_scores<<<dim3(4, 4, NH), 256, 0, stream>>>(qb, kb, sc);
  k_softmax<<<NH * TT, 256, 0, stream>>>(sc, Pb);
  k_pv<<<dim3(4, 1, NH), 256, 0, stream>>>(Pb, vtb, o_in);
  k_gemm_o<<<64, 256, 0, stream>>>(o_in, wo, xb, hidden);
  k_rms2<<<TT, 256, 0, stream>>>(hidden, ln2, h2);
  k_gemm_gu<<<384, 256, 0, stream>>>(h2, wgu, gu);
  k_silu<<<dim3(INTR / 256, TT), 256, 0, stream>>>(gu, act);
  k_gemm_down<<<64, 256, 0, stream>>>(act, wdn, hidden, out0);
}

// Round 2
// 501.758 us; speedup vs baseline: 1.6016x; 1.6016x over previous
//
#include <hip/hip_runtime.h>

#define TT 512
#define HIDD 2048
#define NH 16
#define NKV 8
#define DD 128
#define INTR 6144
#define SEQ 4096
#define SCALE 0.08838834764831845f

typedef __attribute__((ext_vector_type(8))) short short8;
typedef __attribute__((ext_vector_type(4))) float floatx4;

static __device__ __forceinline__ unsigned short f2b(float f) {
  unsigned int u = __float_as_uint(f);
  u += 0x7fffu + ((u >> 16) & 1u);
  return (unsigned short)(u >> 16);
}

// ---------------- GEMM core with register-prefetch pipeline ----------------
// C(128x128) += A(128x[kbeg:kend]) * B(128x[kbeg:kend])^T
// LDS rows padded to 40 bf16 (80B = 5*16B: 16B-aligned, 2-way bank alias = free)

template <bool H>
struct TileRegs {
  float4 f[4];
  short8 h[2];
};

template <bool H>
static __device__ __forceinline__ void tile_load(const void* __restrict__ src, int ld, int k0,
                                                 int tid, TileRegs<H>& r) {
  if constexpr (H) {
    const unsigned short* s = (const unsigned short*)src;
    const int r0 = tid >> 2, c8 = (tid & 3) << 3;
#pragma unroll
    for (int i = 0; i < 2; ++i)
      r.h[i] = *reinterpret_cast<const short8*>(s + (size_t)(r0 + (i << 6)) * ld + k0 + c8);
  } else {
    const float* s = (const float*)src;
    const int r0 = tid >> 3, c4 = (tid & 7) << 2;
#pragma unroll
    for (int i = 0; i < 4; ++i)
      r.f[i] = *reinterpret_cast<const float4*>(s + (size_t)(r0 + (i << 5)) * ld + k0 + c4);
  }
}

template <bool H>
static __device__ __forceinline__ void tile_store(const TileRegs<H>& r, unsigned short* dst, int tid) {
  if constexpr (H) {
    const int r0 = tid >> 2, c8 = (tid & 3) << 3;
#pragma unroll
    for (int i = 0; i < 2; ++i)
      *reinterpret_cast<short8*>(dst + (r0 + (i << 6)) * 40 + c8) = r.h[i];
  } else {
    const int r0 = tid >> 3, c4 = (tid & 7) << 2;
#pragma unroll
    for (int i = 0; i < 4; ++i) {
      ushort4 o;
      o.x = f2b(r.f[i].x); o.y = f2b(r.f[i].y); o.z = f2b(r.f[i].z); o.w = f2b(r.f[i].w);
      *reinterpret_cast<ushort4*>(dst + (r0 + (i << 5)) * 40 + c4) = o;
    }
  }
}

template <bool A16, bool B16>
static __device__ __forceinline__ void gemm_core(const void* __restrict__ A, int lda,
                                                 const void* __restrict__ B, int ldb,
                                                 int kbeg, int kend, floatx4 acc[4][4],
                                                 unsigned short* As, unsigned short* Bs) {
  const int tid = threadIdx.x;
  const int lane = tid & 63;
  const int wave = tid >> 6;
  const int wr = (wave >> 1) << 6;
  const int wc = (wave & 1) << 6;
  const int lrow = lane & 15;
  const int koff = (lane >> 4) << 3;
  TileRegs<A16> ra;
  TileRegs<B16> rb;
  tile_load<A16>(A, lda, kbeg, tid, ra);
  tile_load<B16>(B, ldb, kbeg, tid, rb);
  for (int k0 = kbeg; k0 < kend; k0 += 32) {
    tile_store<A16>(ra, As, tid);
    tile_store<B16>(rb, Bs, tid);
    __syncthreads();
    if (k0 + 32 < kend) {  // prefetch next tile; overlaps frag reads + MFMA + barrier
      tile_load<A16>(A, lda, k0 + 32, tid, ra);
      tile_load<B16>(B, ldb, k0 + 32, tid, rb);
    }
    short8 af[4], bfr[4];
#pragma unroll
    for (int mi = 0; mi < 4; ++mi)
      af[mi] = *reinterpret_cast<const short8*>(As + (wr + mi * 16 + lrow) * 40 + koff);
#pragma unroll
    for (int ni = 0; ni < 4; ++ni)
      bfr[ni] = *reinterpret_cast<const short8*>(Bs + (wc + ni * 16 + lrow) * 40 + koff);
#pragma unroll
    for (int mi = 0; mi < 4; ++mi)
#pragma unroll
      for (int ni = 0; ni < 4; ++ni)
        acc[mi][ni] = __builtin_amdgcn_mfma_f32_16x16x32_bf16(af[mi], bfr[ni], acc[mi][ni], 0, 0, 0);
    __syncthreads();
  }
}

#define EPI_VARS \
  const int lane = threadIdx.x & 63; \
  const int wave = threadIdx.x >> 6; \
  const int wr = (wave >> 1) << 6;   \
  const int wc = (wave & 1) << 6;    \
  const int lrow = lane & 15;        \
  const int quad = lane >> 4;

#define ZERO_ACC \
  floatx4 acc[4][4]; \
  _Pragma("unroll") for (int mi = 0; mi < 4; ++mi) \
  _Pragma("unroll") for (int ni = 0; ni < 4; ++ni) { floatx4 z = {0.f,0.f,0.f,0.f}; acc[mi][ni] = z; }

// XCD swizzle: the 4 mt-blocks of one (nt,split) group sit at b, b+8, b+16, b+24
// -> same bid%8 -> same XCD -> B-tile fetched once per XCD L2.
template <int S>
static __device__ __forceinline__ void swz(int b, int& mt, int& nt, int& s) {
  mt = (b >> 3) & 3;
  const int gid = ((b >> 5) << 3) | (b & 7);
  nt = gid / S;
  s = gid - nt * S;
}

// ---------------- kernels ----------------

__global__ __launch_bounds__(256) void k_rms1(const float* __restrict__ conv,
                                              const float* __restrict__ w,
                                              float* __restrict__ xb, float* __restrict__ h1) {
  const int t = blockIdx.x;
  const int tid = threadIdx.x;
  float v[8];
  float ss = 0.f;
#pragma unroll
  for (int i = 0; i < 8; ++i) {
    const int c = tid + (i << 8);
    v[i] = conv[(size_t)c * TT + t];
    ss += v[i] * v[i];
  }
  __shared__ float red[4];
  const int lane = tid & 63, wid = tid >> 6;
#pragma unroll
  for (int o = 32; o; o >>= 1) ss += __shfl_xor(ss, o);
  if (!lane) red[wid] = ss;
  __syncthreads();
  const float tot = red[0] + red[1] + red[2] + red[3];
  const float r = rsqrtf(tot * (1.0f / HIDD) + 1e-6f);
#pragma unroll
  for (int i = 0; i < 8; ++i) {
    const int c = tid + (i << 8);
    xb[(size_t)t * HIDD + c] = v[i];
    h1[(size_t)t * HIDD + c] = v[i] * r * w[c];
  }
}

__global__ __launch_bounds__(256) void k_gemm_qkv(const float* __restrict__ h1,
                                                  const float* __restrict__ wq,
                                                  const float* __restrict__ wk,
                                                  const float* __restrict__ wv,
                                                  float* __restrict__ Pq) {
  __shared__ unsigned short As[128 * 40], Bs[128 * 40];
  int mt, nt, s;
  swz<4>(blockIdx.x, mt, nt, s);          // NT=32, S=4 -> 512 blocks
  const int m0 = mt << 7, n0 = nt << 7;
  const float* Bp;
  if (n0 < 2048)      Bp = wq + (size_t)n0 * HIDD;
  else if (n0 < 3072) Bp = wk + (size_t)(n0 - 2048) * HIDD;
  else                Bp = wv + (size_t)(n0 - 3072) * HIDD;
  ZERO_ACC
  gemm_core<false, false>(h1 + (size_t)m0 * HIDD, HIDD, Bp, HIDD, s * 512, s * 512 + 512, acc, As, Bs);
  EPI_VARS
  float* out = Pq + (size_t)s * (TT * 4096);
#pragma unroll
  for (int mi = 0; mi < 4; ++mi)
#pragma unroll
    for (int ni = 0; ni < 4; ++ni)
#pragma unroll
      for (int rr = 0; rr < 4; ++rr) {
        const int row = m0 + wr + mi * 16 + quad * 4 + rr;
        const int col = n0 + wc + ni * 16 + lrow;
        out[(size_t)row * 4096 + col] = acc[mi][ni][rr];
      }
}

__global__ __launch_bounds__(128) void k_rope(const float* __restrict__ Pq,
                                              const float* __restrict__ cosb,
                                              const float* __restrict__ sinb,
                                              const float* __restrict__ qnw,
                                              const float* __restrict__ knw,
                                              unsigned short* __restrict__ qb,
                                              unsigned short* __restrict__ kb,
                                              unsigned short* __restrict__ vtb,
                                              float* __restrict__ kout,
                                              float* __restrict__ vout) {
  const int u = blockIdx.x;  // 0..15 q-heads, 16..23 k-heads, 24..31 v-heads
  const int t = blockIdx.y;
  const int d = threadIdx.x;
  __shared__ float red[2];
  __shared__ float sh[DD];
  int slot;
  if (u < NH)            slot = u * DD + d;
  else if (u < NH + NKV) slot = 2048 + (u - NH) * DD + d;
  else                   slot = 3072 + (u - NH - NKV) * DD + d;
  const size_t idx = (size_t)t * 4096 + slot;
  float val = Pq[idx] + Pq[idx + TT * 4096] + Pq[idx + 2 * TT * 4096] + Pq[idx + 3 * TT * 4096];
  if (u < NH + NKV) {
    float ss = val * val;
    const int lane = d & 63, wid = d >> 6;
#pragma unroll
    for (int o = 32; o; o >>= 1) ss += __shfl_xor(ss, o);
    if (!lane) red[wid] = ss;
    __syncthreads();
    const float r = rsqrtf((red[0] + red[1]) * (1.0f / DD) + 1e-6f);
    const float w = (u < NH) ? qnw[d] : knw[d];
    const float nv = val * r * w;
    sh[d] = nv;
    __syncthreads();
    const float partner = sh[d ^ 64];
    const float rh = (d < 64) ? -partner : partner;
    const float o = nv * cosb[(size_t)t * DD + d] + rh * sinb[(size_t)t * DD + d];
    if (u < NH) {
      qb[(size_t)u * TT * DD + (size_t)t * DD + d] = f2b(o);
    } else {
      const int kh = u - NH;
      kout[(size_t)kh * SEQ * DD + (size_t)t * DD + d] = o;
      kb[(size_t)kh * TT * DD + (size_t)t * DD + d] = f2b(o);
    }
  } else {
    const int vh = u - NH - NKV;
    vout[(size_t)vh * SEQ * DD + (size_t)t * DD + d] = val;
    vtb[(size_t)vh * DD * TT + (size_t)d * TT + t] = f2b(val);
  }
}

__global__ __launch_bounds__(256) void k_tail(const float* __restrict__ kc,
                                              const float* __restrict__ vc,
                                              float* __restrict__ ko,
                                              float* __restrict__ vo) {
  const int i = blockIdx.x * 256 + threadIdx.x;  // float4 index
  const int e = i << 2;
  const int s = (e >> 7) & (SEQ - 1);
  if (s >= TT) {
    reinterpret_cast<float4*>(ko)[i] = reinterpret_cast<const float4*>(kc)[i];
    reinterpret_cast<float4*>(vo)[i] = reinterpret_cast<const float4*>(vc)[i];
  }
}

__global__ __launch_bounds__(256) void k_scores(const unsigned short* __restrict__ qb,
                                                const unsigned short* __restrict__ kb,
                                                float* __restrict__ sc) {
  __shared__ unsigned short As[128 * 40], Bs[128 * 40];
  const int m0 = blockIdx.x << 7, n0 = blockIdx.y << 7, h = blockIdx.z;
  ZERO_ACC
  gemm_core<true, true>(qb + (size_t)h * TT * DD + (size_t)m0 * DD, DD,
                        kb + (size_t)(h >> 1) * TT * DD + (size_t)n0 * DD, DD, 0, DD, acc, As, Bs);
  EPI_VARS
  float* out = sc + (size_t)h * TT * TT;
#pragma unroll
  for (int mi = 0; mi < 4; ++mi)
#pragma unroll
    for (int ni = 0; ni < 4; ++ni)
#pragma unroll
      for (int rr = 0; rr < 4; ++rr) {
        const int t = m0 + wr + mi * 16 + quad * 4 + rr;
        const int s = n0 + wc + ni * 16 + lrow;
        float v = acc[mi][ni][rr] * SCALE;
        if (s > t) v += -10000.0f;
        out[(size_t)t * TT + s] = v;
      }
}

__global__ __launch_bounds__(256) void k_softmax(const float* __restrict__ sc,
                                                 unsigned short* __restrict__ Pb) {
  const int h = blockIdx.x >> 9, t = blockIdx.x & 511;
  const int tid = threadIdx.x;
  const float* row = sc + ((size_t)h * TT + t) * TT;
  float v0 = row[tid], v1 = row[tid + 256];
  __shared__ float red[4];
  const int lane = tid & 63, wid = tid >> 6;
  float m = fmaxf(v0, v1);
#pragma unroll
  for (int o = 32; o; o >>= 1) m = fmaxf(m, __shfl_xor(m, o));
  if (!lane) red[wid] = m;
  __syncthreads();
  m = fmaxf(fmaxf(red[0], red[1]), fmaxf(red[2], red[3]));
  const float e0 = __expf(v0 - m), e1 = __expf(v1 - m);
  float s = e0 + e1;
  __syncthreads();
#pragma unroll
  for (int o = 32; o; o >>= 1) s += __shfl_xor(s, o);
  if (!lane) red[wid] = s;
  __syncthreads();
  const float inv = 1.0f / (red[0] + red[1] + red[2] + red[3]);
  unsigned short* orow = Pb + ((size_t)h * TT + t) * TT;
  orow[tid] = f2b(e0 * inv);
  orow[tid + 256] = f2b(e1 * inv);
}

__global__ __launch_bounds__(256) void k_pv(const unsigned short* __restrict__ Pb,
                                            const unsigned short* __restrict__ vtb,
                                            float* __restrict__ Ppv) {
  __shared__ unsigned short As[128 * 40], Bs[128 * 40];
  int mt, h, s;
  swz<4>(blockIdx.x, mt, h, s);           // "NT"=16 heads, S=4 -> 256 blocks
  const int m0 = mt << 7;
  ZERO_ACC
  gemm_core<true, true>(Pb + (size_t)h * TT * TT + (size_t)m0 * TT, TT,
                        vtb + (size_t)(h >> 1) * DD * TT, TT, s * 128, s * 128 + 128, acc, As, Bs);
  EPI_VARS
  float* out = Ppv + (size_t)s * (TT * HIDD);
#pragma unroll
  for (int mi = 0; mi < 4; ++mi)
#pragma unroll
    for (int ni = 0; ni < 4; ++ni)
#pragma unroll
      for (int rr = 0; rr < 4; ++rr) {
        const int row = m0 + wr + mi * 16 + quad * 4 + rr;
        const int col = wc + ni * 16 + lrow;
        out[(size_t)row * HIDD + h * DD + col] = acc[mi][ni][rr];
      }
}

__global__ __launch_bounds__(256) void k_red_pv(const float* __restrict__ Ppv,
                                                float* __restrict__ o_in) {
  const int i = blockIdx.x * 256 + threadIdx.x;  // float4 index over 512*2048
  const float4* p = reinterpret_cast<const float4*>(Ppv);
  float4 a = p[i];
  const float4 b = p[i + 262144], c = p[i + 524288], d = p[i + 786432];
  a.x += b.x + c.x + d.x; a.y += b.y + c.y + d.y;
  a.z += b.z + c.z + d.z; a.w += b.w + c.w + d.w;
  reinterpret_cast<float4*>(o_in)[i] = a;
}

__global__ __launch_bounds__(256) void k_gemm_o(const float* __restrict__ o_in,
                                                const float* __restrict__ wo,
                                                float* __restrict__ Po) {
  __shared__ unsigned short As[128 * 40], Bs[128 * 40];
  int mt, nt, s;
  swz<8>(blockIdx.x, mt, nt, s);          // NT=16, S=8 -> 512 blocks
  const int m0 = mt << 7, n0 = nt << 7;
  ZERO_ACC
  gemm_core<false, false>(o_in + (size_t)m0 * HIDD, HIDD, wo + (size_t)n0 * HIDD, HIDD,
                          s * 256, s * 256 + 256, acc, As, Bs);
  EPI_VARS
  float* out = Po + (size_t)s * (TT * HIDD);
#pragma unroll
  for (int mi = 0; mi < 4; ++mi)
#pragma unroll
    for (int ni = 0; ni < 4; ++ni)
#pragma unroll
      for (int rr = 0; rr < 4; ++rr) {
        const int row = m0 + wr + mi * 16 + quad * 4 + rr;
        const int col = n0 + wc + ni * 16 + lrow;
        out[(size_t)row * HIDD + col] = acc[mi][ni][rr];
      }
}

__global__ __launch_bounds__(256) void k_rms2(const float* __restrict__ xb,
                                              const float* __restrict__ Po,
                                              const float* __restrict__ w,
                                              float* __restrict__ hidden,
                                              float* __restrict__ h2) {
  const int t = blockIdx.x;
  const int tid = threadIdx.x;
  float v[8];
  float ss = 0.f;
#pragma unroll
  for (int i = 0; i < 8; ++i) {
    const int c = tid + (i << 8);
    const size_t idx = (size_t)t * HIDD + c;
    float a = xb[idx];
#pragma unroll
    for (int sp = 0; sp < 8; ++sp) a += Po[idx + (size_t)sp * (TT * HIDD)];
    v[i] = a;
    ss += a * a;
  }
  __shared__ float red[4];
  const int lane = tid & 63, wid = tid >> 6;
#pragma unroll
  for (int o = 32; o; o >>= 1) ss += __shfl_xor(ss, o);
  if (!lane) red[wid] = ss;
  __syncthreads();
  const float tot = red[0] + red[1] + red[2] + red[3];
  const float r = rsqrtf(tot * (1.0f / HIDD) + 1e-6f);
#pragma unroll
  for (int i = 0; i < 8; ++i) {
    const int c = tid + (i << 8);
    const size_t idx = (size_t)t * HIDD + c;
    hidden[idx] = v[i];
    h2[idx] = v[i] * r * w[c];
  }
}

__global__ __launch_bounds__(256) void k_gemm_gu(const float* __restrict__ h2,
                                                 const float* __restrict__ wgu,
                                                 float* __restrict__ gu) {
  __shared__ unsigned short As[128 * 40], Bs[128 * 40];
  int mt, nt, s;
  swz<1>(blockIdx.x, mt, nt, s);          // NT=96, S=1 -> 384 blocks
  const int m0 = mt << 7, n0 = nt << 7;
  ZERO_ACC
  gemm_core<false, false>(h2 + (size_t)m0 * HIDD, HIDD, wgu + (size_t)n0 * HIDD, HIDD,
                          0, HIDD, acc, As, Bs);
  EPI_VARS
#pragma unroll
  for (int mi = 0; mi < 4; ++mi)
#pragma unroll
    for (int ni = 0; ni < 4; ++ni)
#pragma unroll
      for (int rr = 0; rr < 4; ++rr) {
        const int row = m0 + wr + mi * 16 + quad * 4 + rr;
        const int col = n0 + wc + ni * 16 + lrow;
        gu[(size_t)row * (2 * INTR) + col] = acc[mi][ni][rr];
      }
}

__global__ __launch_bounds__(256) void k_silu(const float* __restrict__ gu,
                                              float* __restrict__ act) {
  const int j = blockIdx.x * 256 + threadIdx.x;  // 0..6143
  const int t = blockIdx.y;
  const float g = gu[(size_t)t * (2 * INTR) + j];
  const float u = gu[(size_t)t * (2 * INTR) + INTR + j];
  act[(size_t)t * INTR + j] = g / (1.f + __expf(-g)) * u;
}

__global__ __launch_bounds__(256) void k_gemm_down(const float* __restrict__ act,
                                                   const float* __restrict__ wdn,
                                                   float* __restrict__ Pdn) {
  __shared__ unsigned short As[128 * 40], Bs[128 * 40];
  int mt, nt, s;
  swz<8>(blockIdx.x, mt, nt, s);          // NT=16, S=8 -> 512 blocks
  const int m0 = mt << 7, n0 = nt << 7;
  ZERO_ACC
  gemm_core<false, false>(act + (size_t)m0 * INTR, INTR, wdn + (size_t)n0 * INTR, INTR,
                          s * 768, s * 768 + 768, acc, As, Bs);
  EPI_VARS
  float* out = Pdn + (size_t)s * (TT * HIDD);
#pragma unroll
  for (int mi = 0; mi < 4; ++mi)
#pragma unroll
    for (int ni = 0; ni < 4; ++ni)
#pragma unroll
      for (int rr = 0; rr < 4; ++rr) {
        const int row = m0 + wr + mi * 16 + quad * 4 + rr;
        const int col = n0 + wc + ni * 16 + lrow;
        out[(size_t)row * HIDD + col] = acc[mi][ni][rr];
      }
}

__global__ __launch_bounds__(256) void k_final(const float* __restrict__ hidden,
                                               const float* __restrict__ Pdn,
                                               float* __restrict__ out0) {
  __shared__ float tile[32][33];
  const int c0 = blockIdx.x << 5, t0 = blockIdx.y << 5;
  const int tx = threadIdx.x & 31, ty0 = (threadIdx.x >> 5) << 2;
#pragma unroll
  for (int i = 0; i < 4; ++i) {
    const int t = t0 + ty0 + i;
    const size_t idx = (size_t)t * HIDD + c0 + tx;
    float a = hidden[idx];
#pragma unroll
    for (int sp = 0; sp < 8; ++sp) a += Pdn[idx + (size_t)sp * (TT * HIDD)];
    tile[ty0 + i][tx] = a;
  }
  __syncthreads();
#pragma unroll
  for (int i = 0; i < 4; ++i)
    out0[(size_t)(c0 + ty0 + i) * TT + t0 + tx] = tile[tx][ty0 + i];
}

extern "C" void kernel_launch(void* const* d_in, const int* in_sizes, int n_in,
                              void* d_out, int out_size, void* d_ws, size_t ws_size,
                              hipStream_t stream) {
  const float* conv   = (const float*)d_in[0];
  const float* cosb   = (const float*)d_in[1];
  const float* sinb   = (const float*)d_in[2];
  const float* kcache = (const float*)d_in[5];
  const float* vcache = (const float*)d_in[6];
  const float* wq  = (const float*)d_in[7];
  const float* wk  = (const float*)d_in[8];
  const float* wv  = (const float*)d_in[9];
  const float* wo  = (const float*)d_in[10];
  const float* ln1 = (const float*)d_in[11];
  const float* ln2 = (const float*)d_in[12];
  const float* qnw = (const float*)d_in[13];
  const float* knw = (const float*)d_in[14];
  const float* wgu = (const float*)d_in[15];
  const float* wdn = (const float*)d_in[16];

  float* ws = (float*)d_ws;
  // layout (floats), total 17,825,792 f = 71.3 MB (== round-1 proven size)
  float* xb     = ws + 0;                         // 1,048,576
  float* h1     = ws + 1048576;                   // 1,048,576 ; later o_in
  float* o_in   = h1;
  float* h2     = ws + 2097152;                   // 1,048,576
  float* hidden = ws + 3145728;                   // 1,048,576
  unsigned short* qb  = (unsigned short*)(ws + 4194304);  // 16*512*128
  unsigned short* kb  = qb + 1048576;                     // 8*512*128
  unsigned short* vtb = kb + 524288;                      // 8*128*512 (d-major)
  float* act = ws + 5242880;                      // 3,145,728
  float* R   = ws + 8388608;                      // 9,437,184 shared region:
  float* Pq  = R;                                 //  phase 2-3: 4 x 2,097,152
  unsigned short* Pb = (unsigned short*)R;        //  phase 4:  2,097,152 f-slots
  float* sc  = R + 2097152;                       //  phase 4a-b: 4,194,304
  float* Ppv = R + 2097152;                       //  phase 4c-d: 4 x 1,048,576 (over dead sc)
  float* Po  = R;                                 //  phase 5-6: 8 x 1,048,576
  float* gu  = R;                                 //  phase 7-8: 6,291,456
  float* Pdn = R;                                 //  phase 9-10: 8 x 1,048,576

  float* out0 = (float*)d_out;          // (HID, T)
  float* kout = out0 + 1048576;         // (NKV, SEQ, D)
  float* vout = kout + 4194304;         // (NKV, SEQ, D)

  k_rms1<<<TT, 256, 0, stream>>>(conv, ln1, xb, h1);
  k_gemm_qkv<<<512, 256, 0, stream>>>(h1, wq, wk, wv, Pq);
  k_rope<<<dim3(NH + 2 * NKV, TT), 128, 0, stream>>>(Pq, cosb, sinb, qnw, knw, qb, kb, vtb, kout, vout);
  k_tail<<<4096, 256, 0, stream>>>(kcache, vcache, kout, vout);
  k_scores<<<dim3(4, 4, NH), 256, 0, stream>>>(qb, kb, sc);
  k_softmax<<<NH * TT, 256, 0, stream>>>(sc, Pb);
  k_pv<<<256, 256, 0, stream>>>(Pb, vtb, Ppv);
  k_red_pv<<<1024, 256, 0, stream>>>(Ppv, o_in);
  k_gemm_o<<<512, 256, 0, stream>>>(o_in, wo, Po);
  k_rms2<<<TT, 256, 0, stream>>>(xb, Po, ln2, hidden, h2);
  k_gemm_gu<<<384, 256, 0, stream>>>(h2, wgu, gu);
  k_silu<<<dim3(INTR / 256, TT), 256, 0, stream>>>(gu, act);
  k_gemm_down<<<512, 256, 0, stream>>>(act, wdn, Pdn);
  k_final<<<dim3(HIDD / 32, TT / 32), 256, 0, stream>>>(hidden, Pdn, out0);
}

// Round 3
// 482.360 us; speedup vs baseline: 1.6660x; 1.0402x over previous
//
#include <hip/hip_runtime.h>
#include <hip/hip_bf16.h>

#define TT 512
#define HIDD 2048
#define NH 16
#define NKV 8
#define DD 128
#define INTR 6144
#define SEQ 4096
#define SCALE 0.08838834764831845f

typedef __attribute__((ext_vector_type(8))) short short8;
typedef __attribute__((ext_vector_type(4))) float floatx4;

static __device__ __forceinline__ unsigned short f2b(float f) {
  unsigned int u = __float_as_uint(f);
  u += 0x7fffu + ((u >> 16) & 1u);
  return (unsigned short)(u >> 16);
}

static __device__ __forceinline__ unsigned int f2b2(float a, float b) {
  __hip_bfloat162 h = __float22bfloat162_rn(make_float2(a, b));
  return *reinterpret_cast<unsigned int*>(&h);
}

// ---------------- GEMM core: double-buffered LDS, 2-deep load pipeline ----------------
// C(BMx128) += A(BMx[kbeg:kend]) * B(128x[kbeg:kend])^T
// LDS rows padded to 40 bf16 (80B = 5*16B: 16B-aligned, 2-way bank alias = free)

template <int BM, bool H> struct TR;
template <> struct TR<128, true>  { short8 v[2]; };
template <> struct TR<128, false> { float4 v[4]; };
template <> struct TR<64, true>   { short8 v[1]; };
template <> struct TR<64, false>  { float4 v[2]; };

template <int BM, bool H>
static __device__ __forceinline__ void tile_load(const void* __restrict__ src, int ld, int k0,
                                                 int tid, TR<BM, H>& r) {
  if constexpr (H) {
    const unsigned short* s = (const unsigned short*)src;
    const int r0 = tid >> 2, c8 = (tid & 3) << 3;
#pragma unroll
    for (int i = 0; i < BM / 64; ++i)
      r.v[i] = *reinterpret_cast<const short8*>(s + (size_t)(r0 + (i << 6)) * ld + k0 + c8);
  } else {
    const float* s = (const float*)src;
    const int r0 = tid >> 3, c4 = (tid & 7) << 2;
#pragma unroll
    for (int i = 0; i < BM / 32; ++i)
      r.v[i] = *reinterpret_cast<const float4*>(s + (size_t)(r0 + (i << 5)) * ld + k0 + c4);
  }
}

template <int BM, bool H>
static __device__ __forceinline__ void tile_store(const TR<BM, H>& r, unsigned short* dst, int tid) {
  if constexpr (H) {
    const int r0 = tid >> 2, c8 = (tid & 3) << 3;
#pragma unroll
    for (int i = 0; i < BM / 64; ++i)
      *reinterpret_cast<short8*>(dst + (r0 + (i << 6)) * 40 + c8) = r.v[i];
  } else {
    const int r0 = tid >> 3, c4 = (tid & 7) << 2;
#pragma unroll
    for (int i = 0; i < BM / 32; ++i) {
      uint2 o;
      o.x = f2b2(r.v[i].x, r.v[i].y);
      o.y = f2b2(r.v[i].z, r.v[i].w);
      *reinterpret_cast<uint2*>(dst + (r0 + (i << 5)) * 40 + c4) = o;
    }
  }
}

template <int BM, bool A16, bool B16>
static __device__ __forceinline__ void gemm_core(const void* __restrict__ A, int lda,
                                                 const void* __restrict__ B, int ldb,
                                                 int kbeg, int kend, floatx4 (&acc)[BM / 32][4],
                                                 unsigned short* As, unsigned short* Bs) {
  constexpr int MI = BM / 32;
  const int tid = threadIdx.x;
  const int lane = tid & 63;
  const int wave = tid >> 6;
  const int wr = (wave >> 1) * (BM >> 1);
  const int wc = (wave & 1) << 6;
  const int lrow = lane & 15;
  const int koff = (lane >> 4) << 3;
  TR<BM, A16> ra;
  TR<128, B16> rb;
  tile_load<BM, A16>(A, lda, kbeg, tid, ra);
  tile_load<128, B16>(B, ldb, kbeg, tid, rb);
  tile_store<BM, A16>(ra, As, tid);
  tile_store<128, B16>(rb, Bs, tid);
  if (kbeg + 32 < kend) {
    tile_load<BM, A16>(A, lda, kbeg + 32, tid, ra);
    tile_load<128, B16>(B, ldb, kbeg + 32, tid, rb);
  }
  __syncthreads();
  int p = 0;
  for (int k0 = kbeg; k0 < kend; k0 += 32) {
    const unsigned short* Ac = As + p * (BM * 40);
    const unsigned short* Bc = Bs + p * (128 * 40);
    unsigned short* An = As + (p ^ 1) * (BM * 40);
    unsigned short* Bn = Bs + (p ^ 1) * (128 * 40);
    short8 af[MI], bfr[4];
#pragma unroll
    for (int mi = 0; mi < MI; ++mi)
      af[mi] = *reinterpret_cast<const short8*>(Ac + (wr + mi * 16 + lrow) * 40 + koff);
#pragma unroll
    for (int ni = 0; ni < 4; ++ni)
      bfr[ni] = *reinterpret_cast<const short8*>(Bc + (wc + ni * 16 + lrow) * 40 + koff);
    if (k0 + 32 < kend) {
      tile_store<BM, A16>(ra, An, tid);
      tile_store<128, B16>(rb, Bn, tid);
      if (k0 + 64 < kend) {
        tile_load<BM, A16>(A, lda, k0 + 64, tid, ra);
        tile_load<128, B16>(B, ldb, k0 + 64, tid, rb);
      }
    }
#pragma unroll
    for (int mi = 0; mi < MI; ++mi)
#pragma unroll
      for (int ni = 0; ni < 4; ++ni)
        acc[mi][ni] = __builtin_amdgcn_mfma_f32_16x16x32_bf16(af[mi], bfr[ni], acc[mi][ni], 0, 0, 0);
    __syncthreads();
    p ^= 1;
  }
}

#define EPI_VARS \
  const int lane = threadIdx.x & 63; \
  const int wave = threadIdx.x >> 6; \
  const int wc = (wave & 1) << 6;    \
  const int lrow = lane & 15;        \
  const int quad = lane >> 4;

#define ZERO_ACC(MI_) \
  floatx4 acc[MI_][4]; \
  _Pragma("unroll") for (int mi = 0; mi < MI_; ++mi) \
  _Pragma("unroll") for (int ni = 0; ni < 4; ++ni) { floatx4 z = {0.f, 0.f, 0.f, 0.f}; acc[mi][ni] = z; }

// XCD swizzle: 4 mt-blocks of one (nt,split) group at b, b+8, b+16, b+24 -> same bid%8 -> same XCD
template <int S>
static __device__ __forceinline__ void swz(int b, int& mt, int& nt, int& s) {
  mt = (b >> 3) & 3;
  const int gid = ((b >> 5) << 3) | (b & 7);
  nt = gid / S;
  s = gid - nt * S;
}

// ---------------- kernels ----------------

__global__ __launch_bounds__(1024) void k_rms1(const float* __restrict__ conv,
                                               const float* __restrict__ w,
                                               float* __restrict__ xb,
                                               unsigned short* __restrict__ h1b) {
  const int t0 = blockIdx.x << 5;  // 16 blocks x 32 t
  const int tid = threadIdx.x;
  const int j = tid & 31;   // t-lane (phase1) / c-lane (phase2 out)
  const int g = tid >> 5;   // c-row 0..31
  __shared__ float part[32][32];
  __shared__ float tile[32][33];
  __shared__ float rs[32];
  float ss = 0.f;
  for (int c0 = 0; c0 < HIDD; c0 += 32) {
    const float v = conv[(size_t)(c0 + g) * TT + t0 + j];
    ss += v * v;
  }
  part[g][j] = ss;
  __syncthreads();
  if (g == 0) {
    float tot = 0.f;
#pragma unroll
    for (int q = 0; q < 32; ++q) tot += part[q][j];
    rs[j] = rsqrtf(tot * (1.0f / HIDD) + 1e-6f);
  }
  __syncthreads();
  for (int c0 = 0; c0 < HIDD; c0 += 32) {
    tile[g][j] = conv[(size_t)(c0 + g) * TT + t0 + j];
    __syncthreads();
    const float v = tile[j][g];  // j = c index, g = t index
    const float rv = rs[g];
    xb[(size_t)(t0 + g) * HIDD + c0 + j] = v;
    h1b[(size_t)(t0 + g) * HIDD + c0 + j] = f2b(v * rv * w[c0 + j]);
    __syncthreads();
  }
}

__global__ __launch_bounds__(256) void k_gemm_qkv(const unsigned short* __restrict__ h1b,
                                                  const float* __restrict__ wq,
                                                  const float* __restrict__ wk,
                                                  const float* __restrict__ wv,
                                                  float* __restrict__ Pq) {
  __shared__ unsigned short As[2 * 128 * 40], Bs[2 * 128 * 40];
  int mt, nt, s;
  swz<4>(blockIdx.x, mt, nt, s);  // NT=32, S=4 -> 512 blocks
  const int m0 = mt << 7, n0 = nt << 7;
  const float* Bp;
  if (n0 < 2048)      Bp = wq + (size_t)n0 * HIDD;
  else if (n0 < 3072) Bp = wk + (size_t)(n0 - 2048) * HIDD;
  else                Bp = wv + (size_t)(n0 - 3072) * HIDD;
  ZERO_ACC(4)
  gemm_core<128, true, false>(h1b + (size_t)m0 * HIDD, HIDD, Bp, HIDD, s * 512, s * 512 + 512, acc, As, Bs);
  EPI_VARS
  const int wr = (wave >> 1) << 6;
  float* out = Pq + (size_t)s * (TT * 4096);
#pragma unroll
  for (int mi = 0; mi < 4; ++mi)
#pragma unroll
    for (int ni = 0; ni < 4; ++ni)
#pragma unroll
      for (int rr = 0; rr < 4; ++rr) {
        const int row = m0 + wr + mi * 16 + quad * 4 + rr;
        const int col = n0 + wc + ni * 16 + lrow;
        out[(size_t)row * 4096 + col] = acc[mi][ni][rr];
      }
}

__global__ __launch_bounds__(128) void k_rope(const float* __restrict__ Pq,
                                              const float* __restrict__ cosb,
                                              const float* __restrict__ sinb,
                                              const float* __restrict__ qnw,
                                              const float* __restrict__ knw,
                                              unsigned short* __restrict__ qb,
                                              unsigned short* __restrict__ kb,
                                              unsigned short* __restrict__ vtb,
                                              float* __restrict__ kout,
                                              float* __restrict__ vout) {
  const int u = blockIdx.x;  // 0..15 q, 16..23 k, 24..31 v
  const int t = blockIdx.y;
  const int d = threadIdx.x;
  __shared__ float red[2];
  __shared__ float sh[DD];
  int slot;
  if (u < NH)            slot = u * DD + d;
  else if (u < NH + NKV) slot = 2048 + (u - NH) * DD + d;
  else                   slot = 3072 + (u - NH - NKV) * DD + d;
  const size_t idx = (size_t)t * 4096 + slot;
  float val = Pq[idx] + Pq[idx + TT * 4096] + Pq[idx + 2 * TT * 4096] + Pq[idx + 3 * TT * 4096];
  if (u < NH + NKV) {
    float ss = val * val;
    const int lane = d & 63, wid = d >> 6;
#pragma unroll
    for (int o = 32; o; o >>= 1) ss += __shfl_xor(ss, o);
    if (!lane) red[wid] = ss;
    __syncthreads();
    const float r = rsqrtf((red[0] + red[1]) * (1.0f / DD) + 1e-6f);
    const float w = (u < NH) ? qnw[d] : knw[d];
    const float nv = val * r * w;
    sh[d] = nv;
    __syncthreads();
    const float partner = sh[d ^ 64];
    const float rh = (d < 64) ? -partner : partner;
    const float o = nv * cosb[(size_t)t * DD + d] + rh * sinb[(size_t)t * DD + d];
    if (u < NH) {
      qb[(size_t)u * TT * DD + (size_t)t * DD + d] = f2b(o);
    } else {
      const int kh = u - NH;
      kout[(size_t)kh * SEQ * DD + (size_t)t * DD + d] = o;
      kb[(size_t)kh * TT * DD + (size_t)t * DD + d] = f2b(o);
    }
  } else {
    const int vh = u - NH - NKV;
    vout[(size_t)vh * SEQ * DD + (size_t)t * DD + d] = val;
    vtb[(size_t)vh * DD * TT + (size_t)d * TT + t] = f2b(val);
  }
}

__global__ __launch_bounds__(256) void k_tail(const float* __restrict__ kc,
                                              const float* __restrict__ vc,
                                              float* __restrict__ ko,
                                              float* __restrict__ vo) {
  const int i = blockIdx.x * 256 + threadIdx.x;  // float4 index
  const int e = i << 2;
  const int s = (e >> 7) & (SEQ - 1);
  if (s >= TT) {
    reinterpret_cast<float4*>(ko)[i] = reinterpret_cast<const float4*>(kc)[i];
    reinterpret_cast<float4*>(vo)[i] = reinterpret_cast<const float4*>(vc)[i];
  }
}

__global__ __launch_bounds__(256) void k_scores(const unsigned short* __restrict__ qb,
                                                const unsigned short* __restrict__ kb,
                                                float* __restrict__ sc) {
  __shared__ unsigned short As[2 * 64 * 40], Bs[2 * 128 * 40];
  const int m0 = blockIdx.x << 6, n0 = blockIdx.y << 7, h = blockIdx.z;
  ZERO_ACC(2)
  gemm_core<64, true, true>(qb + (size_t)h * TT * DD + (size_t)m0 * DD, DD,
                            kb + (size_t)(h >> 1) * TT * DD + (size_t)n0 * DD, DD, 0, DD, acc, As, Bs);
  EPI_VARS
  const int wr = (wave >> 1) << 5;
  float* out = sc + (size_t)h * TT * TT;
#pragma unroll
  for (int mi = 0; mi < 2; ++mi)
#pragma unroll
    for (int ni = 0; ni < 4; ++ni)
#pragma unroll
      for (int rr = 0; rr < 4; ++rr) {
        const int t = m0 + wr + mi * 16 + quad * 4 + rr;
        const int s = n0 + wc + ni * 16 + lrow;
        float v = acc[mi][ni][rr] * SCALE;
        if (s > t) v += -10000.0f;
        out[(size_t)t * TT + s] = v;
      }
}

__global__ __launch_bounds__(256) void k_softmax(const float* __restrict__ sc,
                                                 unsigned short* __restrict__ Pb) {
  const int h = blockIdx.x >> 9, t = blockIdx.x & 511;
  const int tid = threadIdx.x;
  const float* row = sc + ((size_t)h * TT + t) * TT;
  float v0 = row[tid], v1 = row[tid + 256];
  __shared__ float red[4];
  const int lane = tid & 63, wid = tid >> 6;
  float m = fmaxf(v0, v1);
#pragma unroll
  for (int o = 32; o; o >>= 1) m = fmaxf(m, __shfl_xor(m, o));
  if (!lane) red[wid] = m;
  __syncthreads();
  m = fmaxf(fmaxf(red[0], red[1]), fmaxf(red[2], red[3]));
  const float e0 = __expf(v0 - m), e1 = __expf(v1 - m);
  float s = e0 + e1;
  __syncthreads();
#pragma unroll
  for (int o = 32; o; o >>= 1) s += __shfl_xor(s, o);
  if (!lane) red[wid] = s;
  __syncthreads();
  const float inv = 1.0f / (red[0] + red[1] + red[2] + red[3]);
  unsigned short* orow = Pb + ((size_t)h * TT + t) * TT;
  orow[tid] = f2b(e0 * inv);
  orow[tid + 256] = f2b(e1 * inv);
}

__global__ __launch_bounds__(256) void k_pv(const unsigned short* __restrict__ Pb,
                                            const unsigned short* __restrict__ vtb,
                                            float* __restrict__ Ppv) {
  __shared__ unsigned short As[2 * 64 * 40], Bs[2 * 128 * 40];
  const int m0 = blockIdx.x << 6, h = blockIdx.y, s = blockIdx.z;
  ZERO_ACC(2)
  gemm_core<64, true, true>(Pb + (size_t)h * TT * TT + (size_t)m0 * TT, TT,
                            vtb + (size_t)(h >> 1) * DD * TT, TT, s * 128, s * 128 + 128, acc, As, Bs);
  EPI_VARS
  const int wr = (wave >> 1) << 5;
  float* out = Ppv + (size_t)s * (TT * HIDD);
#pragma unroll
  for (int mi = 0; mi < 2; ++mi)
#pragma unroll
    for (int ni = 0; ni < 4; ++ni)
#pragma unroll
      for (int rr = 0; rr < 4; ++rr) {
        const int row = m0 + wr + mi * 16 + quad * 4 + rr;
        const int col = wc + ni * 16 + lrow;
        out[(size_t)row * HIDD + h * DD + col] = acc[mi][ni][rr];
      }
}

__global__ __launch_bounds__(256) void k_red_pv(const float* __restrict__ Ppv,
                                                unsigned short* __restrict__ o_inb) {
  const int i = blockIdx.x * 256 + threadIdx.x;  // float4 index over 512*2048/4
  const float4* p = reinterpret_cast<const float4*>(Ppv);
  float4 a = p[i];
  const float4 b = p[i + 262144], c = p[i + 524288], d = p[i + 786432];
  a.x += b.x + c.x + d.x; a.y += b.y + c.y + d.y;
  a.z += b.z + c.z + d.z; a.w += b.w + c.w + d.w;
  uint2 o;
  o.x = f2b2(a.x, a.y);
  o.y = f2b2(a.z, a.w);
  *reinterpret_cast<uint2*>(o_inb + (size_t)i * 4) = o;
}

__global__ __launch_bounds__(256) void k_gemm_o(const unsigned short* __restrict__ o_inb,
                                                const float* __restrict__ wo,
                                                float* __restrict__ Po) {
  __shared__ unsigned short As[2 * 128 * 40], Bs[2 * 128 * 40];
  int mt, nt, s;
  swz<8>(blockIdx.x, mt, nt, s);  // NT=16, S=8 -> 512 blocks
  const int m0 = mt << 7, n0 = nt << 7;
  ZERO_ACC(4)
  gemm_core<128, true, false>(o_inb + (size_t)m0 * HIDD, HIDD, wo + (size_t)n0 * HIDD, HIDD,
                              s * 256, s * 256 + 256, acc, As, Bs);
  EPI_VARS
  const int wr = (wave >> 1) << 6;
  float* out = Po + (size_t)s * (TT * HIDD);
#pragma unroll
  for (int mi = 0; mi < 4; ++mi)
#pragma unroll
    for (int ni = 0; ni < 4; ++ni)
#pragma unroll
      for (int rr = 0; rr < 4; ++rr) {
        const int row = m0 + wr + mi * 16 + quad * 4 + rr;
        const int col = n0 + wc + ni * 16 + lrow;
        out[(size_t)row * HIDD + col] = acc[mi][ni][rr];
      }
}

__global__ __launch_bounds__(256) void k_rms2(const float* __restrict__ xb,
                                              const float* __restrict__ Po,
                                              const float* __restrict__ w,
                                              float* __restrict__ hidden,
                                              unsigned short* __restrict__ h2b) {
  const int t = blockIdx.x;
  const int tid = threadIdx.x;
  float2 v[4];
  float ss = 0.f;
#pragma unroll
  for (int i = 0; i < 4; ++i) {
    const int c = (tid << 1) + (i << 9);
    const size_t idx = (size_t)t * HIDD + c;
    float2 a = *reinterpret_cast<const float2*>(xb + idx);
#pragma unroll
    for (int sp = 0; sp < 8; ++sp) {
      const float2 b = *reinterpret_cast<const float2*>(Po + idx + (size_t)sp * (TT * HIDD));
      a.x += b.x; a.y += b.y;
    }
    v[i] = a;
    ss += a.x * a.x + a.y * a.y;
  }
  __shared__ float red[4];
  const int lane = tid & 63, wid = tid >> 6;
#pragma unroll
  for (int o = 32; o; o >>= 1) ss += __shfl_xor(ss, o);
  if (!lane) red[wid] = ss;
  __syncthreads();
  const float tot = red[0] + red[1] + red[2] + red[3];
  const float r = rsqrtf(tot * (1.0f / HIDD) + 1e-6f);
#pragma unroll
  for (int i = 0; i < 4; ++i) {
    const int c = (tid << 1) + (i << 9);
    const size_t idx = (size_t)t * HIDD + c;
    *reinterpret_cast<float2*>(hidden + idx) = v[i];
    const float2 wv2 = *reinterpret_cast<const float2*>(w + c);
    *reinterpret_cast<unsigned int*>(h2b + idx) = f2b2(v[i].x * r * wv2.x, v[i].y * r * wv2.y);
  }
}

__global__ __launch_bounds__(256) void k_gemm_gu(const unsigned short* __restrict__ h2b,
                                                 const float* __restrict__ wgu,
                                                 float* __restrict__ gu) {
  __shared__ unsigned short As[2 * 64 * 40], Bs[2 * 128 * 40];
  const int bid = blockIdx.x;       // 768 = 8 mt x 96 nt
  const int mt = bid / 96, nt = bid - mt * 96;  // bid%8 == nt%8 -> same nt same XCD
  const int m0 = mt << 6, n0 = nt << 7;
  ZERO_ACC(2)
  gemm_core<64, true, false>(h2b + (size_t)m0 * HIDD, HIDD, wgu + (size_t)n0 * HIDD, HIDD,
                             0, HIDD, acc, As, Bs);
  EPI_VARS
  const int wr = (wave >> 1) << 5;
#pragma unroll
  for (int mi = 0; mi < 2; ++mi)
#pragma unroll
    for (int ni = 0; ni < 4; ++ni)
#pragma unroll
      for (int rr = 0; rr < 4; ++rr) {
        const int row = m0 + wr + mi * 16 + quad * 4 + rr;
        const int col = n0 + wc + ni * 16 + lrow;
        gu[(size_t)row * (2 * INTR) + col] = acc[mi][ni][rr];
      }
}

__global__ __launch_bounds__(256) void k_silu(const float* __restrict__ gu,
                                              unsigned short* __restrict__ actb) {
  const int j0 = (blockIdx.x * 256 + threadIdx.x) << 1;  // grid.x = 12
  const int t = blockIdx.y;
  const float2 g = *reinterpret_cast<const float2*>(gu + (size_t)t * (2 * INTR) + j0);
  const float2 u = *reinterpret_cast<const float2*>(gu + (size_t)t * (2 * INTR) + INTR + j0);
  const float a0 = g.x / (1.f + __expf(-g.x)) * u.x;
  const float a1 = g.y / (1.f + __expf(-g.y)) * u.y;
  *reinterpret_cast<unsigned int*>(actb + (size_t)t * INTR + j0) = f2b2(a0, a1);
}

__global__ __launch_bounds__(256) void k_gemm_down(const unsigned short* __restrict__ actb,
                                                   const float* __restrict__ wdn,
                                                   float* __restrict__ Pdn) {
  __shared__ unsigned short As[2 * 128 * 40], Bs[2 * 128 * 40];
  int mt, nt, s;
  swz<8>(blockIdx.x, mt, nt, s);  // NT=16, S=8 -> 512 blocks
  const int m0 = mt << 7, n0 = nt << 7;
  ZERO_ACC(4)
  gemm_core<128, true, false>(actb + (size_t)m0 * INTR, INTR, wdn + (size_t)n0 * INTR, INTR,
                              s * 768, s * 768 + 768, acc, As, Bs);
  EPI_VARS
  const int wr = (wave >> 1) << 6;
  float* out = Pdn + (size_t)s * (TT * HIDD);
#pragma unroll
  for (int mi = 0; mi < 4; ++mi)
#pragma unroll
    for (int ni = 0; ni < 4; ++ni)
#pragma unroll
      for (int rr = 0; rr < 4; ++rr) {
        const int row = m0 + wr + mi * 16 + quad * 4 + rr;
        const int col = n0 + wc + ni * 16 + lrow;
        out[(size_t)row * HIDD + col] = acc[mi][ni][rr];
      }
}

__global__ __launch_bounds__(256) void k_final(const float* __restrict__ hidden,
                                               const float* __restrict__ Pdn,
                                               float* __restrict__ out0) {
  __shared__ float tile[32][33];
  const int c0 = blockIdx.x << 5, t0 = blockIdx.y << 5;
  const int tx = threadIdx.x & 31, ty0 = (threadIdx.x >> 5) << 2;
#pragma unroll
  for (int i = 0; i < 4; ++i) {
    const int t = t0 + ty0 + i;
    const size_t idx = (size_t)t * HIDD + c0 + tx;
    float a = hidden[idx];
#pragma unroll
    for (int sp = 0; sp < 8; ++sp) a += Pdn[idx + (size_t)sp * (TT * HIDD)];
    tile[ty0 + i][tx] = a;
  }
  __syncthreads();
#pragma unroll
  for (int i = 0; i < 4; ++i)
    out0[(size_t)(c0 + ty0 + i) * TT + t0 + tx] = tile[tx][ty0 + i];
}

extern "C" void kernel_launch(void* const* d_in, const int* in_sizes, int n_in,
                              void* d_out, int out_size, void* d_ws, size_t ws_size,
                              hipStream_t stream) {
  const float* conv   = (const float*)d_in[0];
  const float* cosb   = (const float*)d_in[1];
  const float* sinb   = (const float*)d_in[2];
  const float* kcache = (const float*)d_in[5];
  const float* vcache = (const float*)d_in[6];
  const float* wq  = (const float*)d_in[7];
  const float* wk  = (const float*)d_in[8];
  const float* wv  = (const float*)d_in[9];
  const float* wo  = (const float*)d_in[10];
  const float* ln1 = (const float*)d_in[11];
  const float* ln2 = (const float*)d_in[12];
  const float* qnw = (const float*)d_in[13];
  const float* knw = (const float*)d_in[14];
  const float* wgu = (const float*)d_in[15];
  const float* wdn = (const float*)d_in[16];

  float* ws = (float*)d_ws;
  // layout (floats): total 14,155,776 f = 56.6 MB (< 71.3 MB proven in R1/R2)
  float* xb = ws + 0;                                      // 1,048,576
  unsigned short* h1b  = (unsigned short*)(ws + 1048576);  // 524,288 f ; later o_inb
  unsigned short* o_inb = h1b;
  unsigned short* h2b  = (unsigned short*)(ws + 1572864);  // 524,288 f
  float* hidden = ws + 2097152;                            // 1,048,576
  unsigned short* qb  = (unsigned short*)(ws + 3145728);   // 16*512*128 us
  unsigned short* kb  = qb + 1048576;                      // 8*512*128 us
  unsigned short* vtb = kb + 524288;                       // 8*128*512 us (d-major)
  unsigned short* actb = (unsigned short*)(ws + 4194304);  // 512*6144 us = 1,572,864 f
  float* R   = ws + 5767168;                               // 8,388,608 f shared region:
  float* Pq  = R;                                          //  qkv:   4 x 2,097,152
  unsigned short* Pb = (unsigned short*)R;                 //  attn:  2,097,152 f-slots
  float* sc  = R + 2097152;                                //  attn:  4,194,304
  float* Ppv = R + 2097152;                                //  pv:    4 x 1,048,576 (over dead sc)
  float* Po  = R;                                          //  o:     8 x 1,048,576
  float* gu  = R;                                          //  mlp:   6,291,456
  float* Pdn = R;                                          //  down:  8 x 1,048,576

  float* out0 = (float*)d_out;   // (HID, T)
  float* kout = out0 + 1048576;  // (NKV, SEQ, D)
  float* vout = kout + 4194304;  // (NKV, SEQ, D)

  k_rms1<<<16, 1024, 0, stream>>>(conv, ln1, xb, h1b);
  k_gemm_qkv<<<512, 256, 0, stream>>>(h1b, wq, wk, wv, Pq);
  k_rope<<<dim3(NH + 2 * NKV, TT), 128, 0, stream>>>(Pq, cosb, sinb, qnw, knw, qb, kb, vtb, kout, vout);
  k_tail<<<4096, 256, 0, stream>>>(kcache, vcache, kout, vout);
  k_scores<<<dim3(8, 4, NH), 256, 0, stream>>>(qb, kb, sc);
  k_softmax<<<NH * TT, 256, 0, stream>>>(sc, Pb);
  k_pv<<<dim3(8, NH, 4), 256, 0, stream>>>(Pb, vtb, Ppv);
  k_red_pv<<<1024, 256, 0, stream>>>(Ppv, o_inb);
  k_gemm_o<<<512, 256, 0, stream>>>(o_inb, wo, Po);
  k_rms2<<<TT, 256, 0, stream>>>(xb, Po, ln2, hidden, h2b);
  k_gemm_gu<<<768, 256, 0, stream>>>(h2b, wgu, gu);
  k_silu<<<dim3(12, TT), 256, 0, stream>>>(gu, actb);
  k_gemm_down<<<512, 256, 0, stream>>>(actb, wdn, Pdn);
  k_final<<<dim3(HIDD / 32, TT / 32), 256, 0, stream>>>(hidden, Pdn, out0);
}